// Round 3
// baseline (145.397 us; speedup 1.0000x reference)
//
#include <hip/hip_runtime.h>
#include <math.h>

typedef _Float16 f16;
typedef __attribute__((ext_vector_type(8))) _Float16 f16x8;
typedef __attribute__((ext_vector_type(4))) _Float16 f16x4;
typedef __attribute__((ext_vector_type(4))) float f32x4;

constexpr int BATCH = 32;
constexpr int QL = 1024;
constexpr int KL = 1024;
constexpr int D = 128;
constexpr int BQ = 64;    // query rows per block (16 per wave)
constexpr int BK = 64;    // key rows per tile
constexpr int DKP = 136;  // sK row pitch in halves (272 B, mult of 16 B)
constexpr int BKP = 72;   // sVT/sP row pitch in halves (144 B, mult of 8 B)

// scale * log2(e): softmax computed in exp2 domain
#define CSC 0.12752863187087177f

__global__ __launch_bounds__(256, 3)
void attn_fwd(const float* __restrict__ Qp, const float* __restrict__ Kp,
              const float* __restrict__ Vp, const int* __restrict__ VLp,
              float* __restrict__ Op) {
  __shared__ f16 sK[BK][DKP];    // K tile, ROW-PERMUTED: pos p holds key (p&15)*4+(p>>4)
  __shared__ f16 sVT[D][BKP];    // V tile transposed [d][kk] (natural kk order)
  __shared__ f16 sP[4][16][BKP]; // per-wave P tile [row][kk] (natural kk order)

  const int tid  = threadIdx.x;
  const int wave = tid >> 6, lane = tid & 63;
  const int l16  = lane & 15, quad = lane >> 4;

  // XCD-affinity swizzle: batch b -> XCD b%8 (round-robin dispatch heuristic)
  const int id  = blockIdx.x;
  const int b   = (( (id >> 3) & 3) << 3) | (id & 7);
  const int qt  = id >> 5;
  const int vl  = VLp[b];

  // ---- Q fragments (A-operand layout), registers for all K tiles
  const float* Qb = Qp + ((size_t)(b * QL + qt * BQ + wave * 16 + l16)) * D;
  f16x8 qfrag[4];
  #pragma unroll
  for (int kc = 0; kc < 4; ++kc) {
    const float* p = Qb + kc * 32 + quad * 8;
    float4 u = *(const float4*)p;
    float4 v = *(const float4*)(p + 4);
    f16x8 f;
    f[0] = (f16)u.x; f[1] = (f16)u.y; f[2] = (f16)u.z; f[3] = (f16)u.w;
    f[4] = (f16)v.x; f[5] = (f16)v.y; f[6] = (f16)v.z; f[7] = (f16)v.w;
    qfrag[kc] = f;
  }

  float m2[4]   = {-INFINITY, -INFINITY, -INFINITY, -INFINITY};
  float lsum[4] = {0.f, 0.f, 0.f, 0.f};
  f32x4 o[8];
  #pragma unroll
  for (int dt = 0; dt < 8; ++dt) o[dt] = (f32x4){0.f, 0.f, 0.f, 0.f};

  const float* Kb = Kp + (size_t)b * KL * D;
  const float* Vb = Vp + (size_t)b * KL * D;
  const int ntiles = (vl + BK - 1) / BK;  // fully-masked tiles contribute exactly 0

  // prefetch registers for next tile (kept live across compute)
  float4 kreg[8], vreg[8];

  // ---- prefetch tile 0
  {
    const float4* Kt = (const float4*)Kb;
    #pragma unroll
    for (int i = 0; i < 8; ++i) kreg[i] = Kt[tid + i * 256];
    #pragma unroll
    for (int i = 0; i < 2; ++i) {
      int f = tid + i * 256;
      const float* base = Vb + (size_t)((f & 15) * 4) * D + (f >> 4) * 4;
      vreg[i * 4 + 0] = *(const float4*)(base);
      vreg[i * 4 + 1] = *(const float4*)(base + D);
      vreg[i * 4 + 2] = *(const float4*)(base + 2 * D);
      vreg[i * 4 + 3] = *(const float4*)(base + 3 * D);
    }
  }

  for (int t = 0; t < ntiles; ++t) {
    // ---- drain prefetch regs into LDS (fp32 -> fp16)
    // K: thread f covers global row f>>5; permuted LDS row (row&3)*16+(row>>2)
    #pragma unroll
    for (int i = 0; i < 8; ++i) {
      int f = tid + i * 256;
      int row = f >> 5, c4 = f & 31;
      int rp = (row & 3) * 16 + (row >> 2);
      float4 u = kreg[i];
      f16x4 h;
      h[0] = (f16)u.x; h[1] = (f16)u.y; h[2] = (f16)u.z; h[3] = (f16)u.w;
      *(f16x4*)&sK[rp][c4 * 4] = h;
    }
    // V transposed, natural kk order
    #pragma unroll
    for (int i = 0; i < 2; ++i) {
      int f = tid + i * 256;
      int k0 = (f & 15) * 4, d0 = (f >> 4) * 4;
      float4 r0 = vreg[i * 4 + 0], r1 = vreg[i * 4 + 1];
      float4 r2 = vreg[i * 4 + 2], r3 = vreg[i * 4 + 3];
      f16x4 h;
      h[0] = (f16)r0.x; h[1] = (f16)r1.x; h[2] = (f16)r2.x; h[3] = (f16)r3.x;
      *(f16x4*)&sVT[d0 + 0][k0] = h;
      h[0] = (f16)r0.y; h[1] = (f16)r1.y; h[2] = (f16)r2.y; h[3] = (f16)r3.y;
      *(f16x4*)&sVT[d0 + 1][k0] = h;
      h[0] = (f16)r0.z; h[1] = (f16)r1.z; h[2] = (f16)r2.z; h[3] = (f16)r3.z;
      *(f16x4*)&sVT[d0 + 2][k0] = h;
      h[0] = (f16)r0.w; h[1] = (f16)r1.w; h[2] = (f16)r2.w; h[3] = (f16)r3.w;
      *(f16x4*)&sVT[d0 + 3][k0] = h;
    }
    __syncthreads();

    // ---- issue global prefetch for tile t+1 (clamped; hidden behind compute)
    {
      int tn = (t + 1 < ntiles) ? t + 1 : t;
      const float4* Kt = (const float4*)(Kb + (size_t)tn * BK * D);
      #pragma unroll
      for (int i = 0; i < 8; ++i) kreg[i] = Kt[tid + i * 256];
      const float* Vt = Vb + (size_t)tn * BK * D;
      #pragma unroll
      for (int i = 0; i < 2; ++i) {
        int f = tid + i * 256;
        const float* base = Vt + (size_t)((f & 15) * 4) * D + (f >> 4) * 4;
        vreg[i * 4 + 0] = *(const float4*)(base);
        vreg[i * 4 + 1] = *(const float4*)(base + D);
        vreg[i * 4 + 2] = *(const float4*)(base + 2 * D);
        vreg[i * 4 + 3] = *(const float4*)(base + 3 * D);
      }
    }

    // ---- S = Q K^T : 4 col-tiles x 4 k-steps of 16x16x32 MFMA
    // LDS row ct*16+l16 holds actual key kk = l16*4 + ct (permuted staging)
    f32x4 s[4];
    #pragma unroll
    for (int ct = 0; ct < 4; ++ct) {
      f32x4 c = (f32x4){0.f, 0.f, 0.f, 0.f};
      #pragma unroll
      for (int kc = 0; kc < 4; ++kc) {
        f16x8 kf = *(const f16x8*)&sK[ct * 16 + l16][kc * 32 + quad * 8];
        c = __builtin_amdgcn_mfma_f32_16x16x32_f16(qfrag[kc], kf, c, 0, 0, 0);
      }
      s[ct] = c;
    }

    // ---- scale into log2 domain + key-padding mask (kk = t*64 + l16*4 + ct)
    #pragma unroll
    for (int ct = 0; ct < 4; ++ct) {
      bool ok = (t * BK + l16 * 4 + ct) < vl;
      #pragma unroll
      for (int r = 0; r < 4; ++r)
        s[ct][r] = ok ? s[ct][r] * CSC : -1.0e9f;
    }

    // ---- online softmax: 16-lane group owns rows quad*4+r
    float mnew[4], alpha[4], ls[4];
    #pragma unroll
    for (int r = 0; r < 4; ++r) {
      float v = fmaxf(fmaxf(s[0][r], s[1][r]), fmaxf(s[2][r], s[3][r]));
      v = fmaxf(v, __shfl_xor(v, 1));
      v = fmaxf(v, __shfl_xor(v, 2));
      v = fmaxf(v, __shfl_xor(v, 4));
      v = fmaxf(v, __shfl_xor(v, 8));
      mnew[r]  = fmaxf(m2[r], v);
      alpha[r] = __builtin_amdgcn_exp2f(m2[r] - mnew[r]);
      m2[r]    = mnew[r];
      ls[r]    = 0.f;
    }
    #pragma unroll
    for (int ct = 0; ct < 4; ++ct)
      #pragma unroll
      for (int r = 0; r < 4; ++r) {
        float p = __builtin_amdgcn_exp2f(s[ct][r] - mnew[r]);
        s[ct][r] = p;
        ls[r] += p;
      }
    #pragma unroll
    for (int r = 0; r < 4; ++r) {
      float v = ls[r];
      v += __shfl_xor(v, 1);
      v += __shfl_xor(v, 2);
      v += __shfl_xor(v, 4);
      v += __shfl_xor(v, 8);
      lsum[r] = lsum[r] * alpha[r] + v;
    }

    // ---- P -> LDS: lane's 4 ct-values are kk-contiguous (l16*4+ct) -> b64 x4
    #pragma unroll
    for (int r = 0; r < 4; ++r) {
      f16x4 h;
      h[0] = (f16)s[0][r]; h[1] = (f16)s[1][r];
      h[2] = (f16)s[2][r]; h[3] = (f16)s[3][r];
      *(f16x4*)&sP[wave][quad * 4 + r][l16 * 4] = h;
    }
    #pragma unroll
    for (int dt = 0; dt < 8; ++dt)
      #pragma unroll
      for (int r = 0; r < 4; ++r)
        o[dt][r] *= alpha[r];

    // sP is wave-private: in-wave DS ordering + waitcnt suffices
    asm volatile("s_waitcnt lgkmcnt(0)" ::: "memory");

    // ---- O += P V
    #pragma unroll
    for (int ks = 0; ks < 2; ++ks) {
      f16x8 pf = *(const f16x8*)&sP[wave][l16][ks * 32 + quad * 8];
      #pragma unroll
      for (int dt = 0; dt < 8; ++dt) {
        f16x8 vf = *(const f16x8*)&sVT[dt * 16 + l16][ks * 32 + quad * 8];
        o[dt] = __builtin_amdgcn_mfma_f32_16x16x32_f16(pf, vf, o[dt], 0, 0, 0);
      }
    }
    __syncthreads();  // all waves done reading sK/sVT before next drain
  }

  // ---- epilogue: O /= l, C-layout store (64B segments per 16 lanes)
  float* Ob = Op + ((size_t)(b * QL + qt * BQ + wave * 16)) * D;
  #pragma unroll
  for (int r = 0; r < 4; ++r) {
    float inv = 1.0f / lsum[r];
    int row = quad * 4 + r;
    #pragma unroll
    for (int dt = 0; dt < 8; ++dt)
      Ob[(size_t)row * D + dt * 16 + l16] = o[dt][r] * inv;
  }
}

extern "C" void kernel_launch(void* const* d_in, const int* in_sizes, int n_in,
                              void* d_out, int out_size, void* d_ws, size_t ws_size,
                              hipStream_t stream) {
  const float* Qp = (const float*)d_in[0];
  const float* Kp = (const float*)d_in[1];
  const float* Vp = (const float*)d_in[2];
  const int*   VL = (const int*)d_in[3];
  float* Op = (float*)d_out;

  attn_fwd<<<dim3(QL / BQ * BATCH), dim3(256), 0, stream>>>(Qp, Kp, Vp, VL, Op);
}

// Round 4
// 129.983 us; speedup vs baseline: 1.1186x; 1.1186x over previous
//
#include <hip/hip_runtime.h>
#include <math.h>

typedef _Float16 f16;
typedef __attribute__((ext_vector_type(8))) _Float16 f16x8;
typedef __attribute__((ext_vector_type(4))) _Float16 f16x4;
typedef __attribute__((ext_vector_type(4))) float f32x4;

constexpr int BATCH = 32;
constexpr int QL = 1024;
constexpr int KL = 1024;
constexpr int D = 128;
constexpr int BQ = 64;    // query rows per block (16 per wave)
constexpr int BK = 64;    // key rows per tile
constexpr int DKP = 136;  // sK row pitch in halves (272 B, mult of 16 B)
constexpr int BKP = 72;   // sVT/sP row pitch in halves (144 B)

// scale * log2(e): softmax computed in exp2 domain
#define CSC 0.12752863187087177f

__global__ __launch_bounds__(256, 2)
void attn_fwd(const float* __restrict__ Qp, const float* __restrict__ Kp,
              const float* __restrict__ Vp, const int* __restrict__ VLp,
              float* __restrict__ Op) {
  // double-buffered tiles: ONE barrier per K-tile
  __shared__ f16 sK[2][BK][DKP];   // K tile, ROW-PERMUTED: pos p holds key (p&15)*4+(p>>4)
  __shared__ f16 sVT[2][D][BKP];   // V tile transposed [d][kk]
  __shared__ f16 sP[4][16][BKP];   // per-wave P tile [row][kk]

  const int tid  = threadIdx.x;
  const int wave = tid >> 6, lane = tid & 63;
  const int l16  = lane & 15, quad = lane >> 4;

  // XCD-affinity swizzle: batch b -> XCD b%8 (kept: FETCH 100->45 MB in R3)
  const int id = blockIdx.x;
  const int b  = (((id >> 3) & 3) << 3) | (id & 7);
  const int qt = id >> 5;
  const int vl = VLp[b];

  const float* Kb = Kp + (size_t)b * KL * D;
  const float* Vb = Vp + (size_t)b * KL * D;
  const int ntiles = (vl + BK - 1) / BK;  // fully-masked tiles contribute exactly 0

  // staging-thread decomposition (same for every tile)
  const int kf_row[8] = {  // K: thread covers global row f>>5, 8 chunks
    (tid + 0*256) >> 5, (tid + 1*256) >> 5, (tid + 2*256) >> 5, (tid + 3*256) >> 5,
    (tid + 4*256) >> 5, (tid + 5*256) >> 5, (tid + 6*256) >> 5, (tid + 7*256) >> 5 };
  const int kf_c4 = tid & 31;

  float4 kreg[8], vreg[8];

  // ---- prologue: load tile 0 into regs
  {
    const float4* Kt = (const float4*)Kb;
    #pragma unroll
    for (int i = 0; i < 8; ++i) kreg[i] = Kt[tid + i * 256];
    #pragma unroll
    for (int i = 0; i < 2; ++i) {
      int f = tid + i * 256;
      const float* base = Vb + (size_t)((f & 15) * 4) * D + (f >> 4) * 4;
      vreg[i * 4 + 0] = *(const float4*)(base);
      vreg[i * 4 + 1] = *(const float4*)(base + D);
      vreg[i * 4 + 2] = *(const float4*)(base + 2 * D);
      vreg[i * 4 + 3] = *(const float4*)(base + 3 * D);
    }
  }

  // ---- Q fragments (A-operand layout), registers for all K tiles
  const float* Qb = Qp + ((size_t)(b * QL + qt * BQ + wave * 16 + l16)) * D;
  f16x8 qfrag[4];
  #pragma unroll
  for (int kc = 0; kc < 4; ++kc) {
    const float* p = Qb + kc * 32 + quad * 8;
    float4 u = *(const float4*)p;
    float4 v = *(const float4*)(p + 4);
    f16x8 f;
    f[0] = (f16)u.x; f[1] = (f16)u.y; f[2] = (f16)u.z; f[3] = (f16)u.w;
    f[4] = (f16)v.x; f[5] = (f16)v.y; f[6] = (f16)v.z; f[7] = (f16)v.w;
    qfrag[kc] = f;
  }

  float m2[4]   = {-INFINITY, -INFINITY, -INFINITY, -INFINITY};
  float lsum[4] = {0.f, 0.f, 0.f, 0.f};
  f32x4 o[8];
  #pragma unroll
  for (int dt = 0; dt < 8; ++dt) o[dt] = (f32x4){0.f, 0.f, 0.f, 0.f};

  // ---- drain tile 0 into buffer 0
  #pragma unroll
  for (int i = 0; i < 8; ++i) {
    int row = kf_row[i];
    int rp = (row & 3) * 16 + (row >> 2);
    float4 u = kreg[i];
    f16x4 h;
    h[0] = (f16)u.x; h[1] = (f16)u.y; h[2] = (f16)u.z; h[3] = (f16)u.w;
    *(f16x4*)&sK[0][rp][kf_c4 * 4] = h;
  }
  #pragma unroll
  for (int i = 0; i < 2; ++i) {
    int f = tid + i * 256;
    int k0 = (f & 15) * 4, d0 = (f >> 4) * 4;
    float4 r0 = vreg[i * 4 + 0], r1 = vreg[i * 4 + 1];
    float4 r2 = vreg[i * 4 + 2], r3 = vreg[i * 4 + 3];
    f16x4 h;
    h[0] = (f16)r0.x; h[1] = (f16)r1.x; h[2] = (f16)r2.x; h[3] = (f16)r3.x;
    *(f16x4*)&sVT[0][d0 + 0][k0] = h;
    h[0] = (f16)r0.y; h[1] = (f16)r1.y; h[2] = (f16)r2.y; h[3] = (f16)r3.y;
    *(f16x4*)&sVT[0][d0 + 1][k0] = h;
    h[0] = (f16)r0.z; h[1] = (f16)r1.z; h[2] = (f16)r2.z; h[3] = (f16)r3.z;
    *(f16x4*)&sVT[0][d0 + 2][k0] = h;
    h[0] = (f16)r0.w; h[1] = (f16)r1.w; h[2] = (f16)r2.w; h[3] = (f16)r3.w;
    *(f16x4*)&sVT[0][d0 + 3][k0] = h;
  }
  __syncthreads();

  for (int t = 0; t < ntiles; ++t) {
    const int cur = t & 1, nxt = cur ^ 1;
    const bool more = (t + 1 < ntiles);

    // ---- issue global loads for tile t+1 (land during compute; VGPR budget
    //      of launch_bounds(256,2) keeps them hoisted here)
    if (more) {
      const float4* Kt = (const float4*)(Kb + (size_t)(t + 1) * BK * D);
      #pragma unroll
      for (int i = 0; i < 8; ++i) kreg[i] = Kt[tid + i * 256];
      const float* Vt = Vb + (size_t)(t + 1) * BK * D;
      #pragma unroll
      for (int i = 0; i < 2; ++i) {
        int f = tid + i * 256;
        const float* base = Vt + (size_t)((f & 15) * 4) * D + (f >> 4) * 4;
        vreg[i * 4 + 0] = *(const float4*)(base);
        vreg[i * 4 + 1] = *(const float4*)(base + D);
        vreg[i * 4 + 2] = *(const float4*)(base + 2 * D);
        vreg[i * 4 + 3] = *(const float4*)(base + 3 * D);
      }
    }

    // ---- S = Q K^T : 4 col-tiles x 4 k-steps of 16x16x32 MFMA
    // LDS row ct*16+l16 holds actual key kk = l16*4 + ct (permuted staging)
    f32x4 s[4];
    #pragma unroll
    for (int ct = 0; ct < 4; ++ct) {
      f32x4 c = (f32x4){0.f, 0.f, 0.f, 0.f};
      #pragma unroll
      for (int kc = 0; kc < 4; ++kc) {
        f16x8 kf = *(const f16x8*)&sK[cur][ct * 16 + l16][kc * 32 + quad * 8];
        c = __builtin_amdgcn_mfma_f32_16x16x32_f16(qfrag[kc], kf, c, 0, 0, 0);
      }
      s[ct] = c;
    }

    // ---- scale into log2 domain + key-padding mask (kk = t*64 + l16*4 + ct)
    #pragma unroll
    for (int ct = 0; ct < 4; ++ct) {
      bool ok = (t * BK + l16 * 4 + ct) < vl;
      #pragma unroll
      for (int r = 0; r < 4; ++r)
        s[ct][r] = ok ? s[ct][r] * CSC : -1.0e9f;
    }

    // ---- online softmax: 16-lane group owns rows quad*4+r
    float mnew[4], alpha[4], ls[4];
    #pragma unroll
    for (int r = 0; r < 4; ++r) {
      float v = fmaxf(fmaxf(s[0][r], s[1][r]), fmaxf(s[2][r], s[3][r]));
      v = fmaxf(v, __shfl_xor(v, 1));
      v = fmaxf(v, __shfl_xor(v, 2));
      v = fmaxf(v, __shfl_xor(v, 4));
      v = fmaxf(v, __shfl_xor(v, 8));
      mnew[r]  = fmaxf(m2[r], v);
      alpha[r] = __builtin_amdgcn_exp2f(m2[r] - mnew[r]);
      m2[r]    = mnew[r];
      ls[r]    = 0.f;
    }
    #pragma unroll
    for (int ct = 0; ct < 4; ++ct)
      #pragma unroll
      for (int r = 0; r < 4; ++r) {
        float p = __builtin_amdgcn_exp2f(s[ct][r] - mnew[r]);
        s[ct][r] = p;
        ls[r] += p;
      }
    #pragma unroll
    for (int r = 0; r < 4; ++r) {
      float v = ls[r];
      v += __shfl_xor(v, 1);
      v += __shfl_xor(v, 2);
      v += __shfl_xor(v, 4);
      v += __shfl_xor(v, 8);
      lsum[r] = lsum[r] * alpha[r] + v;
    }

    // ---- P -> LDS: lane's 4 ct-values are kk-contiguous (l16*4+ct) -> b64 x4
    #pragma unroll
    for (int r = 0; r < 4; ++r) {
      f16x4 h;
      h[0] = (f16)s[0][r]; h[1] = (f16)s[1][r];
      h[2] = (f16)s[2][r]; h[3] = (f16)s[3][r];
      *(f16x4*)&sP[wave][quad * 4 + r][l16 * 4] = h;
    }
    #pragma unroll
    for (int dt = 0; dt < 8; ++dt)
      #pragma unroll
      for (int r = 0; r < 4; ++r)
        o[dt][r] *= alpha[r];

    // sP is wave-private: in-wave DS ordering + waitcnt suffices
    asm volatile("s_waitcnt lgkmcnt(0)" ::: "memory");

    // ---- O += P V
    #pragma unroll
    for (int ks = 0; ks < 2; ++ks) {
      f16x8 pf = *(const f16x8*)&sP[wave][l16][ks * 32 + quad * 8];
      #pragma unroll
      for (int dt = 0; dt < 8; ++dt) {
        f16x8 vf = *(const f16x8*)&sVT[cur][dt * 16 + l16][ks * 32 + quad * 8];
        o[dt] = __builtin_amdgcn_mfma_f32_16x16x32_f16(pf, vf, o[dt], 0, 0, 0);
      }
    }

    // ---- drain prefetch regs into the other buffer (loads had full compute
    //      period to land; vmcnt hits 0 here so the barrier drain is free)
    if (more) {
      #pragma unroll
      for (int i = 0; i < 8; ++i) {
        int row = kf_row[i];
        int rp = (row & 3) * 16 + (row >> 2);
        float4 u = kreg[i];
        f16x4 h;
        h[0] = (f16)u.x; h[1] = (f16)u.y; h[2] = (f16)u.z; h[3] = (f16)u.w;
        *(f16x4*)&sK[nxt][rp][kf_c4 * 4] = h;
      }
      #pragma unroll
      for (int i = 0; i < 2; ++i) {
        int f = tid + i * 256;
        int k0 = (f & 15) * 4, d0 = (f >> 4) * 4;
        float4 r0 = vreg[i * 4 + 0], r1 = vreg[i * 4 + 1];
        float4 r2 = vreg[i * 4 + 2], r3 = vreg[i * 4 + 3];
        f16x4 h;
        h[0] = (f16)r0.x; h[1] = (f16)r1.x; h[2] = (f16)r2.x; h[3] = (f16)r3.x;
        *(f16x4*)&sVT[nxt][d0 + 0][k0] = h;
        h[0] = (f16)r0.y; h[1] = (f16)r1.y; h[2] = (f16)r2.y; h[3] = (f16)r3.y;
        *(f16x4*)&sVT[nxt][d0 + 1][k0] = h;
        h[0] = (f16)r0.z; h[1] = (f16)r1.z; h[2] = (f16)r2.z; h[3] = (f16)r3.z;
        *(f16x4*)&sVT[nxt][d0 + 2][k0] = h;
        h[0] = (f16)r0.w; h[1] = (f16)r1.w; h[2] = (f16)r2.w; h[3] = (f16)r3.w;
        *(f16x4*)&sVT[nxt][d0 + 3][k0] = h;
      }
    }
    __syncthreads();
  }

  // ---- epilogue: O /= l, C-layout store (64B segments per 16 lanes)
  float* Ob = Op + ((size_t)(b * QL + qt * BQ + wave * 16)) * D;
  #pragma unroll
  for (int r = 0; r < 4; ++r) {
    float inv = 1.0f / lsum[r];
    int row = quad * 4 + r;
    #pragma unroll
    for (int dt = 0; dt < 8; ++dt)
      Ob[(size_t)row * D + dt * 16 + l16] = o[dt][r] * inv;
  }
}

extern "C" void kernel_launch(void* const* d_in, const int* in_sizes, int n_in,
                              void* d_out, int out_size, void* d_ws, size_t ws_size,
                              hipStream_t stream) {
  const float* Qp = (const float*)d_in[0];
  const float* Kp = (const float*)d_in[1];
  const float* Vp = (const float*)d_in[2];
  const int*   VL = (const int*)d_in[3];
  float* Op = (float*)d_out;

  attn_fwd<<<dim3(QL / BQ * BATCH), dim3(256), 0, stream>>>(Qp, Kp, Vp, VL, Op);
}